// Round 4
// baseline (284.308 us; speedup 1.0000x reference)
//
#include <hip/hip_runtime.h>
#include <math.h>

namespace {
constexpr int Bn = 32, Hn = 1024, Wn = 1024;
constexpr int STRIP = 16;                     // rows per block (divides Hn)
constexpr int GRID1 = Bn * Hn / STRIP;        // 2048 blocks -> 8 blocks/CU
constexpr float BWGT = 3.0f;
}

__device__ inline float4 vmax4(float4 a, float4 b) {
    return make_float4(fmaxf(a.x,b.x), fmaxf(a.y,b.y), fmaxf(a.z,b.z), fmaxf(a.w,b.w));
}
__device__ inline float4 vmin4(float4 a, float4 b) {
    return make_float4(fminf(a.x,b.x), fminf(a.y,b.y), fminf(a.z,b.z), fminf(a.w,b.w));
}

// R4: rolling 3-row window inside a #pragma unroll 1 loop.
// R0-R3 established: the burst-all-28-loads-then-compute shape leaves each
// wave issuing NOTHING for ~15K cycles after a ~60-cycle load burst; with all
// resident waves in phase, the CU alternates memory-spike / memory-silent
// phases and both pipes idle (~24% each, 2.5 TB/s effective vs 6.3 ceiling).
// A non-unrolled per-row loop gives continuous issue (copy-kernel dynamics,
// m13-style) AND bounds register liveness to one iteration -- the compiler
// CANNOT hoist loads across an unroll-1 loop-carried pointer, which is what
// bloated R2 to 148 VGPR. Target: <=64 VGPR -> 8 waves/SIMD.
// Halo columns for lanes 0/63 re-read from global (exec-masked 4B loads,
// L1-hit on neighbor's lines; proven exact, absmax 0.0 in R2/R3).
// Image borders use binary-target identities (0 for max, 1 for min) ==
// reduce_window's -inf/+inf padding, exact.
__global__ __launch_bounds__(256) void bam_bce_rows(
    const float* __restrict__ pred, const float* __restrict__ tgt,
    float* __restrict__ partial)
{
    const int tid  = threadIdx.x;
    const int lane = tid & 63;
    const int x0   = tid << 2;
    const int rowBase = blockIdx.x * STRIP;   // strips never cross images
    const int y0 = rowBase & (Hn - 1);
    const bool vtop = (y0 != 0);              // row y0-1 exists (block-uniform)
    const bool vbot = (y0 != Hn - STRIP);     // row y0+STRIP exists
    const float* tb = tgt  + (size_t)rowBase * Wn;
    const float* pb = pred + (size_t)rowBase * Wn;

    // halo-column loaders: lane 0 reads x0-1 (left neighbor's .w), lane 63
    // reads x0+4 (right neighbor's .x); image-border lanes load nothing.
    const bool isL = (lane == 0)  && (tid != 0);
    const bool isR = (lane == 63) && (tid != 255);
    const bool isEdge = isL || isR;
    const int  nbx = isL ? (x0 - 1) : (x0 + 4);   // only deref'd if isEdge

    const float4 z4 = make_float4(0.f, 0.f, 0.f, 0.f);

    // ---- prolog: rows -1, 0, 1 of target (+halo), rows 0, 1 of pred ----
    float4 t_prev = z4, t_cur, t_next;
    float nb_prev = 0.f, nb_cur = 0.f, nb_next = 0.f;
    if (vtop) {
        t_prev = *reinterpret_cast<const float4*>(tb - Wn + x0);
        if (isEdge) nb_prev = tb[nbx - Wn];
    }
    t_cur  = *reinterpret_cast<const float4*>(tb + x0);
    t_next = *reinterpret_cast<const float4*>(tb + Wn + x0);
    if (isEdge) {
        nb_cur  = tb[nbx];
        nb_next = tb[Wn + nbx];
    }
    float4 p_cur  = *reinterpret_cast<const float4*>(pb + x0);
    float4 p_next = *reinterpret_cast<const float4*>(pb + Wn + x0);

    const float* tb2 = tb + 2 * (size_t)Wn;   // walking base for row i+2
    const float* pb2 = pb + 2 * (size_t)Wn;

    float sum = 0.0f;
    #pragma unroll 1
    for (int i = 0; i < STRIP; ++i) {
        // ---- prefetch row i+2 (consumed next iteration) ----
        float4 t_nn = z4, p_nn = z4;
        float nb_nn = 0.f;
        const bool ldT = (i < STRIP - 2) || ((i == STRIP - 2) && vbot);
        const bool ldP = (i < STRIP - 2);
        if (ldT) {
            t_nn = *reinterpret_cast<const float4*>(tb2 + x0);
            if (isEdge) nb_nn = tb2[nbx];
        }
        if (ldP) p_nn = *reinterpret_cast<const float4*>(pb2 + x0);
        tb2 += Wn; pb2 += Wn;

        const bool useTop = (i > 0) || vtop;           // row i-1 valid
        const bool useBot = (i < STRIP - 1) || vbot;   // row i+1 valid

        // vertical (3-row) max/min for own 4 columns + this lane's halo col
        float4 mx = t_cur, mn = t_cur;
        float  em = nb_cur, en = nb_cur;
        if (useTop) {
            mx = vmax4(mx, t_prev); mn = vmin4(mn, t_prev);
            em = fmaxf(em, nb_prev); en = fminf(en, nb_prev);
        }
        if (useBot) {
            mx = vmax4(mx, t_next); mn = vmin4(mn, t_next);
            em = fmaxf(em, nb_next); en = fminf(en, nb_next);
        }

        // horizontal neighbors: in-wave shuffle, patched at wave/image edges
        float Lmx = __shfl_up(mx.w, 1),   Lmn = __shfl_up(mn.w, 1);
        float Rmx = __shfl_down(mx.x, 1), Rmn = __shfl_down(mn.x, 1);
        if (lane == 0)  { Lmx = em; Lmn = en; }
        if (lane == 63) { Rmx = em; Rmn = en; }
        if (tid == 0)   { Lmx = 0.f; Lmn = 1.f; }      // image left border
        if (tid == 255) { Rmx = 0.f; Rmn = 1.f; }      // image right border

        const float4 t = t_cur;
        const float4 p = p_cur;
        {
            const float wmx = fmaxf(fmaxf(Lmx, mx.x), mx.y);
            const float wmn = fminf(fminf(Lmn, mn.x), mn.y);
            const float w = (wmx > wmn) ? BWGT : 1.0f;
            const float x = (t.x != 0.0f) ? p.x : (1.0f - p.x);
            sum = fmaf(w, -__logf(x), sum);
        }
        {
            const float wmx = fmaxf(fmaxf(mx.x, mx.y), mx.z);
            const float wmn = fminf(fminf(mn.x, mn.y), mn.z);
            const float w = (wmx > wmn) ? BWGT : 1.0f;
            const float x = (t.y != 0.0f) ? p.y : (1.0f - p.y);
            sum = fmaf(w, -__logf(x), sum);
        }
        {
            const float wmx = fmaxf(fmaxf(mx.y, mx.z), mx.w);
            const float wmn = fminf(fminf(mn.y, mn.z), mn.w);
            const float w = (wmx > wmn) ? BWGT : 1.0f;
            const float x = (t.z != 0.0f) ? p.z : (1.0f - p.z);
            sum = fmaf(w, -__logf(x), sum);
        }
        {
            const float wmx = fmaxf(fmaxf(mx.z, mx.w), Rmx);
            const float wmn = fminf(fminf(mn.z, mn.w), Rmn);
            const float w = (wmx > wmn) ? BWGT : 1.0f;
            const float x = (t.w != 0.0f) ? p.w : (1.0f - p.w);
            sum = fmaf(w, -__logf(x), sum);
        }

        // ---- rotate rolling window (named movs; liveness stays 1 iter) ----
        t_prev = t_cur;  t_cur = t_next;  t_next = t_nn;
        nb_prev = nb_cur; nb_cur = nb_next; nb_next = nb_nn;
        p_cur = p_next;  p_next = p_nn;
    }

    // wave(64) shuffle reduce -> 4-wave LDS reduce -> one partial per block
    #pragma unroll
    for (int off = 32; off > 0; off >>= 1) sum += __shfl_down(sum, off);
    __shared__ float smem[4];
    if ((tid & 63) == 0) smem[tid >> 6] = sum;
    __syncthreads();
    if (tid == 0) partial[blockIdx.x] = (smem[0] + smem[1]) + (smem[2] + smem[3]);
}

__global__ __launch_bounds__(256) void bam_bce_reduce(
    const float* __restrict__ partial, float* __restrict__ out)
{
    const int tid = threadIdx.x;
    float s = 0.0f;
    for (int i = tid; i < GRID1; i += 256) s += partial[i];
    #pragma unroll
    for (int off = 32; off > 0; off >>= 1) s += __shfl_down(s, off);
    __shared__ float smem[4];
    if ((tid & 63) == 0) smem[tid >> 6] = s;
    __syncthreads();
    if (tid == 0) {
        const float invN = 1.0f / (float)((long long)Bn * Hn * Wn);  // 1/2^25, exact
        out[0] = ((smem[0] + smem[1]) + (smem[2] + smem[3])) * invN;
    }
}

extern "C" void kernel_launch(void* const* d_in, const int* in_sizes, int n_in,
                              void* d_out, int out_size, void* d_ws, size_t ws_size,
                              hipStream_t stream)
{
    const float* pred = (const float*)d_in[0];
    const float* tgt  = (const float*)d_in[1];
    float* partial = (float*)d_ws;            // 2048 floats = 8 KB, fully
                                              // overwritten each call (poison-safe)
    bam_bce_rows<<<GRID1, 256, 0, stream>>>(pred, tgt, partial);
    bam_bce_reduce<<<1, 256, 0, stream>>>(partial, (float*)d_out);
}

// Round 5
// 281.147 us; speedup vs baseline: 1.0112x; 1.0112x over previous
//
#include <hip/hip_runtime.h>
#include <math.h>
#include <stdint.h>

namespace {
constexpr int Bn = 32, Hn = 1024, Wn = 1024;
constexpr int STRIP = 8;                      // rows per block (divides Hn)
constexpr int GRID1 = Bn * Hn / STRIP;        // 4096 strips
constexpr int TROWS = STRIP + 2;              // staged target rows (-1 .. STRIP)
constexpr int TSTR  = 1032;                   // 4 pad + 1024 data + 4 pad floats
constexpr float BWGT = 3.0f;
}

__device__ inline float4 vmax4(float4 a, float4 b) {
    return make_float4(fmaxf(a.x,b.x), fmaxf(a.y,b.y), fmaxf(a.z,b.z), fmaxf(a.w,b.w));
}
__device__ inline float4 vmin4(float4 a, float4 b) {
    return make_float4(fminf(a.x,b.x), fminf(a.y,b.y), fminf(a.z,b.z), fminf(a.w,b.w));
}

// Direct global->LDS copy, 16B per lane. Global src addr is PER-LANE; LDS
// dest is wave-uniform base + lane*16 (HW rule). Size must be a literal.
__device__ inline void gload_lds16(const float* g, float* l) {
    __builtin_amdgcn_global_load_lds(
        (const __attribute__((address_space(1))) unsigned int*)(uintptr_t)g,
        (__attribute__((address_space(3))) unsigned int*)(uintptr_t)l,
        16, 0, 0);
}

// R5 theory: R0-R4 swept occupancy 11->64%, VGPR 32->148, barrier/no-barrier,
// burst/rolling -- all pinned at 102-110us, ~10 GB/s/CU read throughput
// (copy kernel: ~25). The invariance to wave count says a per-CU shared
// resource saturates at 4 waves: the L1/VGPR-return miss path. This version
// splits the two streams across load mechanisms: TARGET goes through
// global_load_lds into an LDS tile (bypasses the VGPR return path; GEMM
// staging sustains ~2.5x our per-CU rate on it), PRED stays on the register
// path. Full-width tile kills all wave-edge halo logic (no shuffles, no halo
// loads); only image-border tid 0/255 patches remain, using the binary-target
// identities (0 for max, 1 for min) == reduce_window's -inf/+inf padding.
// XCD-chunked bijective swizzle (4096%8==0) gives adjacent strips (which
// share staged halo rows) same-XCD L2 locality. partial[] is indexed by
// STRIP id, not hardware block id, so summation order -- and the result --
// is bit-identical to prior rounds.
__global__ __launch_bounds__(256) void bam_bce_rows(
    const float* __restrict__ pred, const float* __restrict__ tgt,
    float* __restrict__ partial)
{
    __shared__ __align__(16) float tile[TROWS][TSTR];   // 41,280 B -> 3 blk/CU

    const int tid  = threadIdx.x;
    const int lane = tid & 63;
    const int wv   = tid >> 6;                // 4 waves per block
    const int x0   = tid << 2;                // this thread's 4 columns
    // XCD-chunked swizzle: XCD k (bids == k mod 8) works strips [k*512,(k+1)*512)
    const int strip   = (int)(blockIdx.x & 7) * (GRID1 / 8) + (int)(blockIdx.x >> 3);
    const int rowBase = strip * STRIP;        // strips never cross images
    const int y0 = rowBase & (Hn - 1);
    const bool vtop = (y0 != 0);              // row y0-1 exists (block-uniform)
    const bool vbot = (y0 != Hn - STRIP);     // row y0+STRIP exists
    const float* tb = tgt  + (size_t)rowBase * Wn;
    const float* pb = pred + (size_t)rowBase * Wn;

    // ---- async-stage target rows -1..STRIP into LDS (wave w: rows w,w+4,..) ----
    // Tile row r holds image row rowBase+r-1 at float idx [4..1027]; idx 3 and
    // 1028 are readable-garbage pads (patched at image borders in registers).
    for (int r = wv; r < TROWS; r += 4) {
        const bool valid = (r > 0 || vtop) && (r < TROWS - 1 || vbot);
        if (valid) {
            const float* src = tb + (size_t)(r - 1) * Wn + 4 * lane;
            #pragma unroll
            for (int c = 0; c < 4; ++c)
                gload_lds16(src + 256 * c, &tile[r][4 + 256 * c]);
        }
    }

    // ---- pred burst into registers (register/VGPR-return path) ----
    float4 pv[STRIP];
    #pragma unroll
    for (int r = 0; r < STRIP; ++r)
        pv[r] = *reinterpret_cast<const float4*>(pb + (size_t)r * Wn + x0);

    __syncthreads();   // drains vmcnt: staging + pred all landed

    float sum = 0.0f;
    #pragma unroll
    for (int i = 0; i < STRIP; ++i) {
        const bool useTop = (i > 0) || vtop;           // tile row i valid
        const bool useBot = (i < STRIP - 1) || vbot;   // tile row i+2 valid

        // read 3 tile rows: own 4 cols (b128) + left/right neighbor col (b32).
        // Invalid rows are read unconditionally (garbage) and discarded.
        const float4 m1 = *reinterpret_cast<const float4*>(&tile[i + 1][4 + x0]);
        const float  l1 = tile[i + 1][3 + x0];
        const float  r1 = tile[i + 1][8 + x0];
        const float4 m0 = *reinterpret_cast<const float4*>(&tile[i][4 + x0]);
        const float  l0 = tile[i][3 + x0];
        const float  r0 = tile[i][8 + x0];
        const float4 m2 = *reinterpret_cast<const float4*>(&tile[i + 2][4 + x0]);
        const float  l2 = tile[i + 2][3 + x0];
        const float  r2 = tile[i + 2][8 + x0];

        // vertical (3-row) max/min for 6 columns: L, c0..c3, R
        float4 mx = m1, mn = m1;
        float Lx = l1, Ln = l1, Rx = r1, Rn = r1;
        if (useTop) {
            mx = vmax4(mx, m0); mn = vmin4(mn, m0);
            Lx = fmaxf(Lx, l0); Ln = fminf(Ln, l0);
            Rx = fmaxf(Rx, r0); Rn = fminf(Rn, r0);
        }
        if (useBot) {
            mx = vmax4(mx, m2); mn = vmin4(mn, m2);
            Lx = fmaxf(Lx, l2); Ln = fminf(Ln, l2);
            Rx = fmaxf(Rx, r2); Rn = fminf(Rn, r2);
        }
        if (tid == 0)   { Lx = 0.f; Ln = 1.f; }        // image left border
        if (tid == 255) { Rx = 0.f; Rn = 1.f; }        // image right border

        const float4 t = m1;
        const float4 p = pv[i];
        {
            const float wmx = fmaxf(fmaxf(Lx, mx.x), mx.y);
            const float wmn = fminf(fminf(Ln, mn.x), mn.y);
            const float w = (wmx > wmn) ? BWGT : 1.0f;
            const float x = (t.x != 0.0f) ? p.x : (1.0f - p.x);
            sum = fmaf(w, -__logf(x), sum);
        }
        {
            const float wmx = fmaxf(fmaxf(mx.x, mx.y), mx.z);
            const float wmn = fminf(fminf(mn.x, mn.y), mn.z);
            const float w = (wmx > wmn) ? BWGT : 1.0f;
            const float x = (t.y != 0.0f) ? p.y : (1.0f - p.y);
            sum = fmaf(w, -__logf(x), sum);
        }
        {
            const float wmx = fmaxf(fmaxf(mx.y, mx.z), mx.w);
            const float wmn = fminf(fminf(mn.y, mn.z), mn.w);
            const float w = (wmx > wmn) ? BWGT : 1.0f;
            const float x = (t.z != 0.0f) ? p.z : (1.0f - p.z);
            sum = fmaf(w, -__logf(x), sum);
        }
        {
            const float wmx = fmaxf(fmaxf(mx.z, mx.w), Rx);
            const float wmn = fminf(fminf(mn.z, mn.w), Rn);
            const float w = (wmx > wmn) ? BWGT : 1.0f;
            const float x = (t.w != 0.0f) ? p.w : (1.0f - p.w);
            sum = fmaf(w, -__logf(x), sum);
        }
    }

    // wave(64) shuffle reduce -> 4-wave LDS reduce -> one partial per STRIP
    #pragma unroll
    for (int off = 32; off > 0; off >>= 1) sum += __shfl_down(sum, off);
    __shared__ float smem[4];
    if ((tid & 63) == 0) smem[tid >> 6] = sum;
    __syncthreads();
    if (tid == 0) partial[strip] = (smem[0] + smem[1]) + (smem[2] + smem[3]);
}

__global__ __launch_bounds__(256) void bam_bce_reduce(
    const float* __restrict__ partial, float* __restrict__ out)
{
    const int tid = threadIdx.x;
    float s = 0.0f;
    for (int i = tid; i < GRID1; i += 256) s += partial[i];
    #pragma unroll
    for (int off = 32; off > 0; off >>= 1) s += __shfl_down(s, off);
    __shared__ float smem[4];
    if ((tid & 63) == 0) smem[tid >> 6] = s;
    __syncthreads();
    if (tid == 0) {
        const float invN = 1.0f / (float)((long long)Bn * Hn * Wn);  // 1/2^25, exact
        out[0] = ((smem[0] + smem[1]) + (smem[2] + smem[3])) * invN;
    }
}

extern "C" void kernel_launch(void* const* d_in, const int* in_sizes, int n_in,
                              void* d_out, int out_size, void* d_ws, size_t ws_size,
                              hipStream_t stream)
{
    const float* pred = (const float*)d_in[0];
    const float* tgt  = (const float*)d_in[1];
    float* partial = (float*)d_ws;            // 4096 floats = 16 KB, fully
                                              // overwritten each call (poison-safe)
    bam_bce_rows<<<GRID1, 256, 0, stream>>>(pred, tgt, partial);
    bam_bce_reduce<<<1, 256, 0, stream>>>(partial, (float*)d_out);
}